// Round 1
// baseline (506.769 us; speedup 1.0000x reference)
//
#include <hip/hip_runtime.h>
#include <math.h>

// Problem constants (from setup_inputs): B=16384 rows, C=4096 cols, NBINS=1000.
constexpr int BROWS = 16384;
constexpr int CCOLS = 4096;
constexpr int BLOCK = 512;                 // 8 waves/block, one row per block
constexpr int WAVES = BLOCK / 64;          // 8
constexpr int V4PT  = CCOLS / BLOCK / 4;   // 2 float4 per thread per array

constexpr float F_EPS      = 1e-7f;
constexpr float F_1M_EPS   = 1.0f - 1e-7f;
constexpr float LOG_EPS    = -16.118095651f;   // log(1e-7)
constexpr float LOG_1M_EPS = -1.0000000e-7f;   // log(1 - 1e-7)

__device__ __forceinline__ float wave_reduce_sum(float v) {
#pragma unroll
    for (int m = 32; m > 0; m >>= 1) v += __shfl_xor(v, m, 64);
    return v;
}
__device__ __forceinline__ float wave_reduce_max(float v) {
#pragma unroll
    for (int m = 32; m > 0; m >>= 1) v = fmaxf(v, __shfl_xor(v, m, 64));
    return v;
}
__device__ __forceinline__ double wave_reduce_sum_d(double v) {
#pragma unroll
    for (int m = 32; m > 0; m >>= 1) v += __shfl_xor(v, m, 64);
    return v;
}

// -(bce term): y*log(clip(p)) + (1-y)*log1p(-clip(p)), p = e * (1/s)
__device__ __forceinline__ float nbce_elem(float x, float y, float ex,
                                           float rs, float off) {
    float p = ex * rs;                       // softmax prob (cached exp * 1/sum)
    p = fminf(fmaxf(p, F_EPS), F_1M_EPS);
    // log of clipped p: log is monotone -> clamp log-softmax value directly
    float logp   = fminf(fmaxf(x - off, LOG_EPS), LOG_1M_EPS);
    float log1mp = __logf(1.0f - p);
    return fmaf(y, logp, (1.0f - y) * log1mp);
}

__global__ void __launch_bounds__(BLOCK, 8)   // cap VGPR<=64 -> 8 waves/SIMD
wce_main_kernel(const float* __restrict__ y_pred,
                const float* __restrict__ y_true,
                const float* __restrict__ weights,
                const int*   __restrict__ cond,
                float* __restrict__ partials)   // [BROWS] per-row weighted bce sums
{
    __shared__ float s_max[WAVES];
    __shared__ float s_sum[WAVES];
    __shared__ float s_bce[WAVES];

    const int row  = blockIdx.x;
    const int tid  = threadIdx.x;
    const int wave = tid >> 6;
    const int lane = tid & 63;
    const size_t base = (size_t)row * CCOLS;

    const float4* yp4 = (const float4*)(y_pred + base);
    const float4* yt4 = (const float4*)(y_true + base);

    // ---- issue ALL loads up front: y_pred (used first) then y_true prefetch ----
    float4 v[V4PT];
    float4 t[V4PT];
#pragma unroll
    for (int i = 0; i < V4PT; ++i) v[i] = yp4[tid + BLOCK * i];
#pragma unroll
    for (int i = 0; i < V4PT; ++i) t[i] = yt4[tid + BLOCK * i];

    // ---- pass 1: row max (only needs v) ----
    float lmax = -3.4e38f;
#pragma unroll
    for (int i = 0; i < V4PT; ++i)
        lmax = fmaxf(lmax, fmaxf(fmaxf(v[i].x, v[i].y), fmaxf(v[i].z, v[i].w)));
    lmax = wave_reduce_max(lmax);
    if (lane == 0) s_max[wave] = lmax;
    __syncthreads();
    float m = s_max[0];
#pragma unroll
    for (int i = 1; i < WAVES; ++i) m = fmaxf(m, s_max[i]);

    // ---- pass 2: sum exp(x - m); cache the exp values (saves 1 trans/elem) ----
    float4 e[V4PT];
    float lsum = 0.0f;
#pragma unroll
    for (int i = 0; i < V4PT; ++i) {
        e[i].x = __expf(v[i].x - m);
        e[i].y = __expf(v[i].y - m);
        e[i].z = __expf(v[i].z - m);
        e[i].w = __expf(v[i].w - m);
        lsum += (e[i].x + e[i].y) + (e[i].z + e[i].w);
    }
    lsum = wave_reduce_sum(lsum);
    if (lane == 0) s_sum[wave] = lsum;
    __syncthreads();
    float s = s_sum[0];
#pragma unroll
    for (int i = 1; i < WAVES; ++i) s += s_sum[i];
    const float off = m + __logf(s);        // log-softmax offset: z = x - off
    const float rs  = 1.0f / s;

    // ---- pass 3: weighted clipped BCE from registers ----
    const float w = weights[cond[row]];

    float nb = 0.0f;
#pragma unroll
    for (int i = 0; i < V4PT; ++i) {
        nb += nbce_elem(v[i].x, t[i].x, e[i].x, rs, off);
        nb += nbce_elem(v[i].y, t[i].y, e[i].y, rs, off);
        nb += nbce_elem(v[i].z, t[i].z, e[i].z, rs, off);
        nb += nbce_elem(v[i].w, t[i].w, e[i].w, rs, off);
    }
    nb = wave_reduce_sum(nb);
    if (lane == 0) s_bce[wave] = nb;
    __syncthreads();
    if (tid == 0) {
        float row_nbce = s_bce[0];
#pragma unroll
        for (int i = 1; i < WAVES; ++i) row_nbce += s_bce[i];
        partials[row] = -w * row_nbce;      // positive weighted bce contribution
    }
}

// Reduce BROWS partials (f32) in double, divide, write the scalar loss.
__global__ void __launch_bounds__(256)
wce_reduce_kernel(const float* __restrict__ partials, float* __restrict__ out)
{
    __shared__ double s_part[4];
    const int tid  = threadIdx.x;
    const int wave = tid >> 6;
    const int lane = tid & 63;

    const float4* p4 = (const float4*)partials;
    double s = 0.0;
#pragma unroll
    for (int i = 0; i < BROWS / (256 * 4); ++i) {   // 16 iters
        float4 p = p4[tid + 256 * i];
        s += (double)p.x + (double)p.y + (double)p.z + (double)p.w;
    }
    s = wave_reduce_sum_d(s);
    if (lane == 0) s_part[wave] = s;
    __syncthreads();
    if (tid == 0) {
        double total = (s_part[0] + s_part[1]) + (s_part[2] + s_part[3]);
        out[0] = (float)(total / ((double)BROWS * (double)CCOLS));
    }
}

extern "C" void kernel_launch(void* const* d_in, const int* in_sizes, int n_in,
                              void* d_out, int out_size, void* d_ws, size_t ws_size,
                              hipStream_t stream) {
    const float* y_pred  = (const float*)d_in[0];
    const float* y_true  = (const float*)d_in[1];
    const float* weights = (const float*)d_in[2];
    const int*   cond    = (const int*)d_in[3];
    float* out      = (float*)d_out;
    float* partials = (float*)d_ws;   // BROWS floats = 64 KB scratch

    wce_main_kernel<<<BROWS, BLOCK, 0, stream>>>(y_pred, y_true, weights, cond, partials);
    wce_reduce_kernel<<<1, 256, 0, stream>>>(partials, out);
}